// Round 1
// baseline (310.364 us; speedup 1.0000x reference)
//
#include <hip/hip_runtime.h>
#include <hip/hip_bf16.h>
#include <math.h>

// Sizes
#define NNEI 200   // NN
#define NB   128   // B
#define NFEW 5     // FEW

__device__ __forceinline__ float sigm(float x) { return 1.0f / (1.0f + __expf(-x)); }

// ---------------------------------------------------------------------------
// Kernel 1: neighbor encoder. One block per (side, row):
//   blocks [0,128)   : q_left  -> query_raw[b][0:64]
//   blocks [128,256) : q_right -> query_raw[b][64:128]
//   blocks [256,261) : s_left  -> support_raw[f][0:64]
//   blocks [261,266) : s_right -> support_raw[f][64:128]
// Each wave handles 50 neighbors. Lane layout per neighbor: r = lane>>4 (row
// quad), c = lane&15 (col chunk of 4). Pass p covers rows 4p..4p+3, so lane l
// pass p reads float4 at rel_base + p*64 + l  -> coalesced 1KB per pass.
// acc[p] is the per-lane partial of msgsum[row=4p + (lane>>4)].
// ---------------------------------------------------------------------------
__global__ __launch_bounds__(256) void k_neighbor(
    const int* __restrict__ qlc, const int* __restrict__ qrc,
    const int* __restrict__ slc, const int* __restrict__ srcn,
    const float* __restrict__ qld, const float* __restrict__ qrd,
    const float* __restrict__ sld, const float* __restrict__ srd,
    const float* __restrict__ ent_emb, const float* __restrict__ rel_mat,
    const float* __restrict__ gcn_w, const float* __restrict__ gcn_wb,
    const float* __restrict__ gcn_b,
    float* __restrict__ query_raw, float* __restrict__ support_raw)
{
    const int blk = blockIdx.x;
    const int* conn; const float* degp; float* outp;
    if (blk < 128)      { int b = blk;       conn = qlc  + b * NNEI * 2; degp = qld + b; outp = query_raw   + b * 128; }
    else if (blk < 256) { int b = blk - 128; conn = qrc  + b * NNEI * 2; degp = qrd + b; outp = query_raw   + b * 128 + 64; }
    else if (blk < 261) { int f = blk - 256; conn = slc  + f * NNEI * 2; degp = sld + f; outp = support_raw + f * 128; }
    else                { int f = blk - 261; conn = srcn + f * NNEI * 2; degp = srd + f; outp = support_raw + f * 128 + 64; }

    const int tid  = threadIdx.x;
    const int wave = tid >> 6;
    const int lane = tid & 63;

    float acc[16];
#pragma unroll
    for (int p = 0; p < 16; ++p) acc[p] = 0.f;

    const int n0 = wave * 50, n1 = n0 + 50;
    for (int n = n0; n < n1; ++n) {
        const int rel = conn[2 * n];
        const int ent = conn[2 * n + 1];
        const float4* Rp = reinterpret_cast<const float4*>(rel_mat + (size_t)rel * 4096) + lane;
        const float4  ev = reinterpret_cast<const float4*>(ent_emb + (size_t)ent * 64)[lane & 15];
#pragma unroll
        for (int p = 0; p < 16; ++p) {
            float4 rv = Rp[p * 64];
            acc[p] = fmaf(rv.x, ev.x, acc[p]);
            acc[p] = fmaf(rv.y, ev.y, acc[p]);
            acc[p] = fmaf(rv.z, ev.z, acc[p]);
            acc[p] = fmaf(rv.w, ev.w, acc[p]);
        }
    }

    // reduce across the 16 col-chunk lanes (lane&15)
#pragma unroll
    for (int p = 0; p < 16; ++p) {
        float v = acc[p];
        v += __shfl_xor(v, 1);
        v += __shfl_xor(v, 2);
        v += __shfl_xor(v, 4);
        v += __shfl_xor(v, 8);
        acc[p] = v;
    }

    __shared__ float msg[64];
    if (tid < 64) msg[tid] = 0.f;
    __syncthreads();
    if ((lane & 15) == 0) {
        const int r = lane >> 4;
#pragma unroll
        for (int p = 0; p < 16; ++p) atomicAdd(&msg[4 * p + r], acc[p]);
    }
    __syncthreads();

    // projection: out_i = tanh((msg @ gcn_w + NN*(wb+b)) / deg)
    if (tid < 64) {
        float s = 0.f;
#pragma unroll 8
        for (int j = 0; j < 64; ++j) s = fmaf(msg[j], gcn_w[j * 64 + tid], s);
        s += (float)NNEI * (gcn_wb[tid] + gcn_b[tid]);
        s /= degp[0];
        outp[tid] = tanhf(s);
    }
}

// ---------------------------------------------------------------------------
// Kernel 2: support encoder (MLP + residual + LayerNorm ddof=1), one block
// per row. Rows [0,128) = query, [128,133) = support.
// ---------------------------------------------------------------------------
__global__ __launch_bounds__(256) void k_encoder(
    const float* __restrict__ query_raw, const float* __restrict__ support_raw,
    const float* __restrict__ w1, const float* __restrict__ b1,
    const float* __restrict__ w2, const float* __restrict__ b2,
    const float* __restrict__ lng, const float* __restrict__ lnb,
    float* __restrict__ query_g, float* __restrict__ support_g)
{
    const int blk = blockIdx.x;
    const float* xin; float* xout;
    if (blk < 128) { xin = query_raw + blk * 128;           xout = query_g + blk * 128; }
    else           { xin = support_raw + (blk - 128) * 128; xout = support_g + (blk - 128) * 128; }

    const int t = threadIdx.x;
    __shared__ float x[128];
    __shared__ float h1[256];
    __shared__ float h[128];
    __shared__ float red[8];

    if (t < 128) x[t] = xin[t];
    __syncthreads();

    {   // h1 = relu(x @ w1 + b1), unit t
        float s = b1[t];
#pragma unroll 8
        for (int j = 0; j < 128; ++j) s = fmaf(x[j], w1[j * 256 + t], s);
        h1[t] = fmaxf(s, 0.f);
    }
    __syncthreads();

    if (t < 128) {  // h = h1 @ w2 + b2 + x
        float s = b2[t] + x[t];
#pragma unroll 8
        for (int k = 0; k < 256; ++k) s = fmaf(h1[k], w2[k * 128 + t], s);
        h[t] = s;
    }
    __syncthreads();

    // LayerNorm with ddof=1 over 128 elems
    float v = (t < 128) ? h[t] : 0.f;
#pragma unroll
    for (int m = 32; m >= 1; m >>= 1) v += __shfl_xor(v, m);
    if ((t & 63) == 0) red[t >> 6] = v;
    __syncthreads();
    const float mu = (red[0] + red[1]) * (1.f / 128.f);
    float d = (t < 128) ? (h[t] - mu) : 0.f;
    float v2 = d * d;
#pragma unroll
    for (int m = 32; m >= 1; m >>= 1) v2 += __shfl_xor(v2, m);
    if ((t & 63) == 0) red[4 + (t >> 6)] = v2;
    __syncthreads();
    const float var = (red[4] + red[5]) * (1.f / 127.f);
    const float rs = 1.f / (sqrtf(var) + 0.001f);
    if (t < 128) xout[t] = (h[t] - mu) * rs * lng[t] + lnb[t];
}

// ---------------------------------------------------------------------------
// Kernel 3: fused 4-step LSTM + attention + final dots. 2 batch rows per
// block (64 blocks x 256 threads). Thread t owns gate units
// {t, t+256, t+512, t+768} = (i,f,g,o) of cell t.
// ---------------------------------------------------------------------------
__global__ __launch_bounds__(256) void k_lstm(
    const float* __restrict__ query_g, const float* __restrict__ sgp,
    const float* __restrict__ wih, const float* __restrict__ whh,
    const float* __restrict__ bih, const float* __restrict__ bhh,
    float* __restrict__ outp)
{
    const int t  = threadIdx.x;
    const int b0 = blockIdx.x * 2;

    __shared__ float sgf[5 * 128];
    __shared__ float qg[2][128];
    __shared__ float hrf[2][256];
    __shared__ float hbuf[2][128];
    __shared__ float redw[4][5];

    for (int i = t; i < 640; i += 256) sgf[i] = sgp[i];
    if (t < 128) {
        qg[0][t] = query_g[(size_t)b0 * 128 + t];
        qg[1][t] = query_g[(size_t)(b0 + 1) * 128 + t];
    }
    for (int i = t; i < 512; i += 256) (&hrf[0][0])[i] = 0.f;

    // x_proj = query @ wih + bih + bhh (4 units x 2 rows per thread)
    float xp[2][4];
#pragma unroll
    for (int k = 0; k < 4; ++k) {
        const float bsum = bih[t + 256 * k] + bhh[t + 256 * k];
        xp[0][k] = bsum; xp[1][k] = bsum;
    }
    __syncthreads();
#pragma unroll 4
    for (int j = 0; j < 128; ++j) {
        const float w0 = wih[j * 1024 + t];
        const float w1 = wih[j * 1024 + t + 256];
        const float w2 = wih[j * 1024 + t + 512];
        const float w3 = wih[j * 1024 + t + 768];
        const float q0 = qg[0][j], q1 = qg[1][j];
        xp[0][0] = fmaf(q0, w0, xp[0][0]); xp[0][1] = fmaf(q0, w1, xp[0][1]);
        xp[0][2] = fmaf(q0, w2, xp[0][2]); xp[0][3] = fmaf(q0, w3, xp[0][3]);
        xp[1][0] = fmaf(q1, w0, xp[1][0]); xp[1][1] = fmaf(q1, w1, xp[1][1]);
        xp[1][2] = fmaf(q1, w2, xp[1][2]); xp[1][3] = fmaf(q1, w3, xp[1][3]);
    }

    float c[2] = {0.f, 0.f};
    const int bp = t >> 7, tp = t & 127;

    for (int step = 0; step < 4; ++step) {
        float ga[2][4];
#pragma unroll
        for (int bq = 0; bq < 2; ++bq)
#pragma unroll
            for (int k = 0; k < 4; ++k) ga[bq][k] = xp[bq][k];

#pragma unroll 2
        for (int j = 0; j < 256; ++j) {
            const float w0 = whh[j * 1024 + t];
            const float w1 = whh[j * 1024 + t + 256];
            const float w2 = whh[j * 1024 + t + 512];
            const float w3 = whh[j * 1024 + t + 768];
            const float h0 = hrf[0][j], h1 = hrf[1][j];
            ga[0][0] = fmaf(h0, w0, ga[0][0]); ga[0][1] = fmaf(h0, w1, ga[0][1]);
            ga[0][2] = fmaf(h0, w2, ga[0][2]); ga[0][3] = fmaf(h0, w3, ga[0][3]);
            ga[1][0] = fmaf(h1, w0, ga[1][0]); ga[1][1] = fmaf(h1, w1, ga[1][1]);
            ga[1][2] = fmaf(h1, w2, ga[1][2]); ga[1][3] = fmaf(h1, w3, ga[1][3]);
        }

#pragma unroll
        for (int bq = 0; bq < 2; ++bq) {
            const float iv = sigm(ga[bq][0]);
            const float fv = sigm(ga[bq][1]);
            const float gv = tanhf(ga[bq][2]);
            const float ov = sigm(ga[bq][3]);
            c[bq] = fv * c[bq] + iv * gv;
            const float hrt = ov * tanhf(c[bq]);
            if (t < 128) hbuf[bq][t] = qg[bq][t] + hrt;
        }
        __syncthreads();  // A: gates read done, hbuf ready

        // attention dots: threads (bp, tp) cover 2 rows x 128 cols
        const float hv = hbuf[bp][tp];
        float p0 = hv * sgf[0 * 128 + tp];
        float p1 = hv * sgf[1 * 128 + tp];
        float p2 = hv * sgf[2 * 128 + tp];
        float p3 = hv * sgf[3 * 128 + tp];
        float p4 = hv * sgf[4 * 128 + tp];
#pragma unroll
        for (int m = 32; m >= 1; m >>= 1) {
            p0 += __shfl_xor(p0, m);
            p1 += __shfl_xor(p1, m);
            p2 += __shfl_xor(p2, m);
            p3 += __shfl_xor(p3, m);
            p4 += __shfl_xor(p4, m);
        }
        if ((t & 63) == 0) {
            const int w = t >> 6;
            redw[w][0] = p0; redw[w][1] = p1; redw[w][2] = p2; redw[w][3] = p3; redw[w][4] = p4;
        }
        __syncthreads();  // B: redw ready

        if (step == 3 && t < 10) {
            const int bl = t / 5, s = t % 5;
            outp[(size_t)(b0 + bl) * 5 + s] = redw[2 * bl][s] + redw[2 * bl + 1][s];
        }

        const float d0 = redw[2 * bp][0] + redw[2 * bp + 1][0];
        const float d1 = redw[2 * bp][1] + redw[2 * bp + 1][1];
        const float d2 = redw[2 * bp][2] + redw[2 * bp + 1][2];
        const float d3 = redw[2 * bp][3] + redw[2 * bp + 1][3];
        const float d4 = redw[2 * bp][4] + redw[2 * bp + 1][4];
        const float mx = fmaxf(fmaxf(fmaxf(d0, d1), fmaxf(d2, d3)), d4);
        const float e0 = __expf(d0 - mx), e1 = __expf(d1 - mx), e2 = __expf(d2 - mx),
                    e3 = __expf(d3 - mx), e4 = __expf(d4 - mx);
        const float inv = 1.f / (e0 + e1 + e2 + e3 + e4);
        const float rv = (e0 * sgf[0 * 128 + tp] + e1 * sgf[1 * 128 + tp] +
                          e2 * sgf[2 * 128 + tp] + e3 * sgf[3 * 128 + tp] +
                          e4 * sgf[4 * 128 + tp]) * inv;

        hrf[bp][tp]       = hbuf[bp][tp];  // h part
        hrf[bp][128 + tp] = rv;            // r part
        __syncthreads();  // C: hrf ready for next step
    }
}

// ---------------------------------------------------------------------------
extern "C" void kernel_launch(void* const* d_in, const int* in_sizes, int n_in,
                              void* d_out, int out_size, void* d_ws, size_t ws_size,
                              hipStream_t stream) {
    const int*   qlc = (const int*)d_in[0];
    const int*   qrc = (const int*)d_in[1];
    const int*   slc = (const int*)d_in[2];
    const int*   srcn= (const int*)d_in[3];
    const float* qld = (const float*)d_in[4];
    const float* qrd = (const float*)d_in[5];
    const float* sld = (const float*)d_in[6];
    const float* srd = (const float*)d_in[7];
    const float* ent = (const float*)d_in[8];
    const float* rel = (const float*)d_in[9];
    const float* gw  = (const float*)d_in[10];
    const float* gwb = (const float*)d_in[11];
    const float* gb  = (const float*)d_in[12];
    const float* w1  = (const float*)d_in[13];
    const float* b1  = (const float*)d_in[14];
    const float* w2  = (const float*)d_in[15];
    const float* b2  = (const float*)d_in[16];
    const float* lng = (const float*)d_in[17];
    const float* lnb = (const float*)d_in[18];
    const float* wih = (const float*)d_in[19];
    const float* whh = (const float*)d_in[20];
    const float* bih = (const float*)d_in[21];
    const float* bhh = (const float*)d_in[22];

    float* ws          = (float*)d_ws;
    float* query_raw   = ws;            // 128*128
    float* support_raw = ws + 16384;    // 5*128
    float* query_g     = ws + 17024;    // 128*128
    float* support_g   = ws + 33408;    // 5*128

    float* outp = (float*)d_out;

    hipLaunchKernelGGL(k_neighbor, dim3(266), dim3(256), 0, stream,
                       qlc, qrc, slc, srcn, qld, qrd, sld, srd,
                       ent, rel, gw, gwb, gb, query_raw, support_raw);
    hipLaunchKernelGGL(k_encoder, dim3(133), dim3(256), 0, stream,
                       query_raw, support_raw, w1, b1, w2, b2, lng, lnb,
                       query_g, support_g);
    hipLaunchKernelGGL(k_lstm, dim3(64), dim3(256), 0, stream,
                       query_g, support_g, wih, whh, bih, bhh, outp);
}

// Round 4
// 237.311 us; speedup vs baseline: 1.3078x; 1.3078x over previous
//
#include <hip/hip_runtime.h>
#include <math.h>

#define NNEI 200
#define NB   128
#define NFEW 5
#define NREL 500
#define CAP  256          // per-rel edge-list capacity (lambda=106, P(>256)~1e-30)
#define NDEST 266         // 128 qL + 128 qR + 5 sL + 5 sR msg rows

__device__ __forceinline__ float sigm(float x) { return 1.0f / (1.0f + __expf(-x)); }

// f32 -> bf16 bits, round-to-nearest-even
__device__ __forceinline__ unsigned bf16_rne(float x) {
    unsigned b = __float_as_uint(x);
    return (b + 0x7fffu + ((b >> 16) & 1u)) >> 16;
}

// ws layout (float offsets)
#define OFF_COUNTS 0              // 512 ints
#define OFF_LIST   512            // 500*256 ints
#define OFF_MSG    128512         // 266*64 f32
#define OFF_QRAW   145536         // 128*128
#define OFF_SRAW   161920         // 5*128
#define OFF_QG     162560         // 128*128
#define OFF_SG     178944         // 5*128
#define OFF_WHHP   179584         // 128*512 uint (bf16 pairs, live cols only)
#define OFF_WIHP   245120         // 64*512 uint

// ---------------------------------------------------------------------------
// K1 prep: zero counts+msg; pack live whh/wih columns to bf16 pairs.
// live gate unit v in [0,512): kind=v>>7, cell=v&127 -> src col u=kind*256+cell
// packed[jp][v] = bf16(w[2jp][u]) | bf16(w[2jp+1][u])<<16
// ---------------------------------------------------------------------------
__global__ __launch_bounds__(512) void k_prep(
    const float* __restrict__ whh, const float* __restrict__ wih, float* __restrict__ ws)
{
    const int gt = blockIdx.x * 512 + threadIdx.x;
    int* counts = (int*)(ws + OFF_COUNTS);
    float* msg  = ws + OFF_MSG;
    unsigned* whhp = (unsigned*)(ws + OFF_WHHP);
    unsigned* wihp = (unsigned*)(ws + OFF_WIHP);

    if (gt < 512) counts[gt] = 0;
    if (gt < NDEST * 64) msg[gt] = 0.f;

    if (gt < 65536) {                       // whh: 128 jp x 512 v
        const int v = gt & 511, jp = gt >> 9;
        const int u = ((v >> 7) << 8) + (v & 127);
        const unsigned lo = bf16_rne(whh[(2 * jp) * 1024 + u]);
        const unsigned hi = bf16_rne(whh[(2 * jp + 1) * 1024 + u]);
        whhp[jp * 512 + v] = lo | (hi << 16);
    } else {                                // wih: 64 jp x 512 v
        const int g2 = gt - 65536;          // < 32768
        const int v = g2 & 511, jp = g2 >> 9;
        const int u = ((v >> 7) << 8) + (v & 127);
        const unsigned lo = bf16_rne(wih[(2 * jp) * 1024 + u]);
        const unsigned hi = bf16_rne(wih[(2 * jp + 1) * 1024 + u]);
        wihp[jp * 512 + v] = lo | (hi << 16);
    }
}

// ---------------------------------------------------------------------------
// K2 build: scatter all 53200 edges into per-rel lists. entry = ent | dest<<16
// ---------------------------------------------------------------------------
__global__ __launch_bounds__(512) void k_build(
    const int* __restrict__ qlc, const int* __restrict__ qrc,
    const int* __restrict__ slc, const int* __restrict__ srcn,
    float* __restrict__ ws)
{
    const int e = blockIdx.x * 512 + threadIdx.x;
    if (e >= 53200) return;
    int* counts = (int*)(ws + OFF_COUNTS);
    int* list   = (int*)(ws + OFF_LIST);

    const int* conn; int i, dest;
    if (e < 25600)      { conn = qlc;  i = e;         dest = i / NNEI; }
    else if (e < 51200) { conn = qrc;  i = e - 25600; dest = 128 + i / NNEI; }
    else if (e < 52200) { conn = slc;  i = e - 51200; dest = 256 + i / NNEI; }
    else                { conn = srcn; i = e - 52200; dest = 261 + i / NNEI; }

    const int rel = conn[2 * i];
    const int ent = conn[2 * i + 1];
    const int slot = atomicAdd(&counts[rel], 1);
    if (slot < CAP) list[rel * CAP + slot] = ent | (dest << 16);
}

// ---------------------------------------------------------------------------
// K3 gather: block r stages R[r]^T in LDS once, processes its edge list.
// out[i] = sum_j R[i][j]*e[j]; lane i accumulates, e[j] via shfl broadcast.
// atomicAdd into msg[dest][i].
// ---------------------------------------------------------------------------
__global__ __launch_bounds__(512) void k_gather(
    const float* __restrict__ rel_mat, const float* __restrict__ ent_emb,
    float* __restrict__ ws)
{
    const int r = blockIdx.x;
    const int tid = threadIdx.x;
    const int wave = tid >> 6, lane = tid & 63;
    const int* counts = (const int*)(ws + OFF_COUNTS);
    const int* list   = (const int*)(ws + OFF_LIST) + r * CAP;
    float* msg = ws + OFF_MSG;

    __shared__ float RT[64 * 65];   // RT[j][i] at j*65+i, padded
    for (int base = 0; base < 4096; base += 512) {
        const int idx = base + tid;
        const int i = idx >> 6, j = idx & 63;
        RT[j * 65 + i] = rel_mat[(size_t)r * 4096 + idx];
    }
    __syncthreads();

    const int cnt = min(counts[r], CAP);
    for (int m = wave; m < cnt; m += 8) {
        const int ed = list[m];
        const int ent = ed & 0xffff, dest = ed >> 16;
        const float ev = ent_emb[(size_t)ent * 64 + lane];
        float acc = 0.f;
#pragma unroll 16
        for (int j = 0; j < 64; ++j) {
            const float bj = __shfl(ev, j);
            acc = fmaf(RT[j * 65 + lane], bj, acc);
        }
        atomicAdd(&msg[dest * 64 + lane], acc);
    }
}

// ---------------------------------------------------------------------------
// K4 project: out[t] = tanh((msg @ gcn_w + NNEI*(wb+b)) / deg), 266 blocks.
// ---------------------------------------------------------------------------
__global__ __launch_bounds__(64) void k_project(
    const float* __restrict__ gcn_w, const float* __restrict__ gcn_wb,
    const float* __restrict__ gcn_b,
    const float* __restrict__ qld, const float* __restrict__ qrd,
    const float* __restrict__ sld, const float* __restrict__ srd,
    float* __restrict__ ws)
{
    const int blk = blockIdx.x, t = threadIdx.x;
    const float* msg = ws + OFF_MSG + blk * 64;
    float* qraw = ws + OFF_QRAW;
    float* sraw = ws + OFF_SRAW;
    const float* degp; float* outp;
    if (blk < 128)      { outp = qraw + blk * 128;               degp = qld + blk; }
    else if (blk < 256) { outp = qraw + (blk - 128) * 128 + 64;  degp = qrd + (blk - 128); }
    else if (blk < 261) { outp = sraw + (blk - 256) * 128;       degp = sld + (blk - 256); }
    else                { outp = sraw + (blk - 261) * 128 + 64;  degp = srd + (blk - 261); }

    __shared__ float m[64];
    m[t] = msg[t];
    __syncthreads();
    float s = 0.f;
#pragma unroll 8
    for (int j = 0; j < 64; ++j) s = fmaf(m[j], gcn_w[j * 64 + t], s);
    s += (float)NNEI * (gcn_wb[t] + gcn_b[t]);
    s /= degp[0];
    outp[t] = tanhf(s);
}

// ---------------------------------------------------------------------------
// K5 encoder: MLP + residual + LayerNorm(ddof=1), one block per row.
// ---------------------------------------------------------------------------
__global__ __launch_bounds__(256) void k_encoder(
    const float* __restrict__ w1, const float* __restrict__ b1,
    const float* __restrict__ w2, const float* __restrict__ b2,
    const float* __restrict__ lng, const float* __restrict__ lnb,
    float* __restrict__ ws)
{
    const int blk = blockIdx.x;
    const float* xin; float* xout;
    if (blk < 128) { xin = ws + OFF_QRAW + blk * 128;         xout = ws + OFF_QG + blk * 128; }
    else           { xin = ws + OFF_SRAW + (blk - 128) * 128; xout = ws + OFF_SG + (blk - 128) * 128; }

    const int t = threadIdx.x;
    __shared__ float x[128];
    __shared__ float h1[256];
    __shared__ float h[128];
    __shared__ float red[8];

    if (t < 128) x[t] = xin[t];
    __syncthreads();

    {
        float s = b1[t];
#pragma unroll 8
        for (int j = 0; j < 128; ++j) s = fmaf(x[j], w1[j * 256 + t], s);
        h1[t] = fmaxf(s, 0.f);
    }
    __syncthreads();

    if (t < 128) {
        float s = b2[t] + x[t];
#pragma unroll 8
        for (int k = 0; k < 256; ++k) s = fmaf(h1[k], w2[k * 128 + t], s);
        h[t] = s;
    }
    __syncthreads();

    float v = (t < 128) ? h[t] : 0.f;
#pragma unroll
    for (int m = 32; m >= 1; m >>= 1) v += __shfl_xor(v, m);
    if ((t & 63) == 0) red[t >> 6] = v;
    __syncthreads();
    const float mu = (red[0] + red[1]) * (1.f / 128.f);
    float d = (t < 128) ? (h[t] - mu) : 0.f;
    float v2 = d * d;
#pragma unroll
    for (int m = 32; m >= 1; m >>= 1) v2 += __shfl_xor(v2, m);
    if ((t & 63) == 0) red[4 + (t >> 6)] = v2;
    __syncthreads();
    const float var = (red[4] + red[5]) * (1.f / 127.f);
    const float rs = 1.f / (sqrtf(var) + 0.001f);
    if (t < 128) xout[t] = (h[t] - mu) * rs * lng[t] + lnb[t];
}

// ---------------------------------------------------------------------------
// K6 lstm: 64 blocks x 512 threads, 2 batch rows/block. Only the 512 LIVE
// gate units (cells 0..127 x {i,f,g,o}) are computed — h_r_[:,128:256] is
// dead in the reference. Weights bf16-packed: one uint load = 2 K-steps.
// ---------------------------------------------------------------------------
__global__ __launch_bounds__(512) void k_lstm(
    const float* __restrict__ bih, const float* __restrict__ bhh,
    float* __restrict__ ws, float* __restrict__ outp)
{
    const int t  = threadIdx.x;
    const int b0 = blockIdx.x * 2;
    const unsigned* whhp = (const unsigned*)(ws + OFF_WHHP);
    const unsigned* wihp = (const unsigned*)(ws + OFF_WIHP);
    const float* query_g = ws + OFF_QG;
    const float* sgp     = ws + OFF_SG;

    __shared__ float  sgf[5 * 128];
    __shared__ float2 qg2[2][64];     // query rows as float2
    __shared__ float2 hr2[2][128];    // h_r (256 dims) as float2
    __shared__ float  gbuf[2][512];   // raw gates, v-indexed
    __shared__ float  redw[4][5];

    float* qg = (float*)qg2;          // [2][128]
    float* hr = (float*)hr2;          // [2][256]

    for (int i = t; i < 640; i += 512) sgf[i] = sgp[i];
    if (t < 256) {
        qg[(t >> 7) * 128 + (t & 127)] = query_g[(size_t)(b0 + (t >> 7)) * 128 + (t & 127)];
    }
    for (int i = t; i < 512; i += 512) { hr[i] = 0.f; }  // t<512 covers all

    const int v = t;                  // live gate unit 0..511
    // kind=v>>7, cell=v&127; bias col u = kind*256+cell
    const int u = ((v >> 7) << 8) + (v & 127);

    float xp[2];
    xp[0] = bih[u] + bhh[u];
    xp[1] = xp[0];
    __syncthreads();

#pragma unroll 8
    for (int jp = 0; jp < 64; ++jp) {
        const unsigned w = wihp[jp * 512 + v];
        const float f0 = __uint_as_float(w << 16);
        const float f1 = __uint_as_float(w & 0xffff0000u);
        const float2 q0 = qg2[0][jp], q1 = qg2[1][jp];
        xp[0] = fmaf(f0, q0.x, fmaf(f1, q0.y, xp[0]));
        xp[1] = fmaf(f0, q1.x, fmaf(f1, q1.y, xp[1]));
    }

    float c = 0.f;                    // valid on t<256: row=t>>7, cell=t&127
    const int bp = (t >> 7) & 1, tp = t & 127;

    for (int step = 0; step < 4; ++step) {
        float ga[2];
        ga[0] = xp[0]; ga[1] = xp[1];
#pragma unroll 8
        for (int jp = 0; jp < 128; ++jp) {
            const unsigned w = whhp[jp * 512 + v];
            const float f0 = __uint_as_float(w << 16);
            const float f1 = __uint_as_float(w & 0xffff0000u);
            const float2 h0 = hr2[0][jp], h1 = hr2[1][jp];
            ga[0] = fmaf(f0, h0.x, fmaf(f1, h0.y, ga[0]));
            ga[1] = fmaf(f0, h1.x, fmaf(f1, h1.y, ga[1]));
        }
        gbuf[0][v] = ga[0];
        gbuf[1][v] = ga[1];
        __syncthreads();   // A: gates ready; hr reads done

        float hv = 0.f;
        if (t < 256) {
            const float iv = sigm(gbuf[bp][tp]);
            const float fv = sigm(gbuf[bp][128 + tp]);
            const float gv = tanhf(gbuf[bp][256 + tp]);
            const float ov = sigm(gbuf[bp][384 + tp]);
            c = fv * c + iv * gv;
            hv = qg[bp * 128 + tp] + ov * tanhf(c);
            hr[bp * 256 + tp] = hv;   // h part of h_r
        }

        // attention dots: threads t<256 = 2 rows x 128 cols (waves 0..3)
        float p0 = 0, p1 = 0, p2 = 0, p3 = 0, p4 = 0;
        if (t < 256) {
            p0 = hv * sgf[0 * 128 + tp];
            p1 = hv * sgf[1 * 128 + tp];
            p2 = hv * sgf[2 * 128 + tp];
            p3 = hv * sgf[3 * 128 + tp];
            p4 = hv * sgf[4 * 128 + tp];
#pragma unroll
            for (int m = 32; m >= 1; m >>= 1) {
                p0 += __shfl_xor(p0, m);
                p1 += __shfl_xor(p1, m);
                p2 += __shfl_xor(p2, m);
                p3 += __shfl_xor(p3, m);
                p4 += __shfl_xor(p4, m);
            }
            if ((t & 63) == 0) {
                const int w = t >> 6;
                redw[w][0] = p0; redw[w][1] = p1; redw[w][2] = p2;
                redw[w][3] = p3; redw[w][4] = p4;
            }
        }
        __syncthreads();   // B: redw ready

        if (step == 3) {
            if (t < 10) {
                const int bl = t / 5, s = t % 5;
                outp[(size_t)(b0 + bl) * 5 + s] = redw[2 * bl][s] + redw[2 * bl + 1][s];
            }
        }
        if (t < 256) {
            const float d0 = redw[2 * bp][0] + redw[2 * bp + 1][0];
            const float d1 = redw[2 * bp][1] + redw[2 * bp + 1][1];
            const float d2 = redw[2 * bp][2] + redw[2 * bp + 1][2];
            const float d3 = redw[2 * bp][3] + redw[2 * bp + 1][3];
            const float d4 = redw[2 * bp][4] + redw[2 * bp + 1][4];
            const float mx = fmaxf(fmaxf(fmaxf(d0, d1), fmaxf(d2, d3)), d4);
            const float e0 = __expf(d0 - mx), e1 = __expf(d1 - mx), e2 = __expf(d2 - mx),
                        e3 = __expf(d3 - mx), e4 = __expf(d4 - mx);
            const float inv = 1.f / (e0 + e1 + e2 + e3 + e4);
            const float rv = (e0 * sgf[0 * 128 + tp] + e1 * sgf[1 * 128 + tp] +
                              e2 * sgf[2 * 128 + tp] + e3 * sgf[3 * 128 + tp] +
                              e4 * sgf[4 * 128 + tp]) * inv;
            hr[bp * 256 + 128 + tp] = rv;   // r part of h_r
        }
        __syncthreads();   // C: hr ready for next step
    }
}

// ---------------------------------------------------------------------------
extern "C" void kernel_launch(void* const* d_in, const int* in_sizes, int n_in,
                              void* d_out, int out_size, void* d_ws, size_t ws_size,
                              hipStream_t stream) {
    const int*   qlc = (const int*)d_in[0];
    const int*   qrc = (const int*)d_in[1];
    const int*   slc = (const int*)d_in[2];
    const int*   srcn= (const int*)d_in[3];
    const float* qld = (const float*)d_in[4];
    const float* qrd = (const float*)d_in[5];
    const float* sld = (const float*)d_in[6];
    const float* srd = (const float*)d_in[7];
    const float* ent = (const float*)d_in[8];
    const float* rel = (const float*)d_in[9];
    const float* gw  = (const float*)d_in[10];
    const float* gwb = (const float*)d_in[11];
    const float* gb  = (const float*)d_in[12];
    const float* w1  = (const float*)d_in[13];
    const float* b1  = (const float*)d_in[14];
    const float* w2  = (const float*)d_in[15];
    const float* b2  = (const float*)d_in[16];
    const float* lng = (const float*)d_in[17];
    const float* lnb = (const float*)d_in[18];
    const float* wih = (const float*)d_in[19];
    const float* whh = (const float*)d_in[20];
    const float* bih = (const float*)d_in[21];
    const float* bhh = (const float*)d_in[22];

    float* ws   = (float*)d_ws;
    float* outp = (float*)d_out;

    hipLaunchKernelGGL(k_prep,    dim3(192), dim3(512), 0, stream, whh, wih, ws);
    hipLaunchKernelGGL(k_build,   dim3(104), dim3(512), 0, stream, qlc, qrc, slc, srcn, ws);
    hipLaunchKernelGGL(k_gather,  dim3(NREL), dim3(512), 0, stream, rel, ent, ws);
    hipLaunchKernelGGL(k_project, dim3(NDEST), dim3(64), 0, stream,
                       gw, gwb, gb, qld, qrd, sld, srd, ws);
    hipLaunchKernelGGL(k_encoder, dim3(133), dim3(256), 0, stream,
                       w1, b1, w2, b2, lng, lnb, ws);
    hipLaunchKernelGGL(k_lstm,    dim3(64), dim3(512), 0, stream, bih, bhh, ws, outp);
}

// Round 5
// 213.999 us; speedup vs baseline: 1.4503x; 1.1089x over previous
//
#include <hip/hip_runtime.h>
#include <math.h>

#define NNEI 200
#define NREL 500
#define CAP  256
// edge ranges: qlc [0,25600) qrc [25600,51200) slc [51200,52200) srcn [52200,53200)
#define NEDGE 53200

__device__ __forceinline__ float sigm(float x) { return 1.0f / (1.0f + __expf(-x)); }
__device__ __forceinline__ unsigned bf16_rne(float x) {
    unsigned b = __float_as_uint(x);
    return (b + 0x7fffu + ((b >> 16) & 1u)) >> 16;
}

// ws layout (float offsets). Non-stage buffers first so both paths share them.
#define OFF_MSG   0              // 266*64 = 17024 (fallback only)
#define OFF_QG    17024          // 128*128
#define OFF_SG    33408          // 5*128
#define OFF_WHHP  34048          // 128*512 uint
#define OFF_WIHP  99584          // 64*512 uint
#define OFF_STAGE 132352         // 53200*64 f32 (staged path only)
#define NEED_FLOATS (132352 + NEDGE * 64)

// ---------------------------------------------------------------------------
// k_zero (fallback path only): zero msg
// ---------------------------------------------------------------------------
__global__ __launch_bounds__(512) void k_zero(float* __restrict__ ws) {
    const int i = blockIdx.x * 512 + threadIdx.x;
    if (i < 266 * 64) ws[OFF_MSG + i] = 0.f;
}

// ---------------------------------------------------------------------------
// k_gather: one block per rel r. Lane i holds R[i][0..63] in 64 VGPRs.
// Phase 1: scan all 53200 edges (conn is L2-resident), collect matches in LDS.
// Phase 2: per edge (one per wave), e-vector read via wave-uniform loads
// (readfirstlane -> scalar/uniform), 64 v_fma per lane. Zero DS ops in the
// inner loop. STAGED: write per-edge row to stage (unique writer, no atomic);
// else atomicAdd into msg[dest].
// ---------------------------------------------------------------------------
template<bool STAGED>
__global__ __launch_bounds__(512) void k_gather(
    const int* __restrict__ qlc, const int* __restrict__ qrc,
    const int* __restrict__ slc, const int* __restrict__ srcn,
    const float* __restrict__ rel_mat, const float* __restrict__ ent_emb,
    float* __restrict__ ws)
{
    const int r    = blockIdx.x;
    const int tid  = threadIdx.x;
    const int wave = tid >> 6, lane = tid & 63;

    __shared__ int2 lst[CAP];
    __shared__ int  lcnt;
    if (tid == 0) lcnt = 0;

    // R row for this lane (8 redundant wave-copies; L2-resident)
    float Rr[64];
    {
        const float4* Rp = reinterpret_cast<const float4*>(rel_mat + (size_t)r * 4096 + lane * 64);
#pragma unroll
        for (int q = 0; q < 16; ++q) {
            const float4 v = Rp[q];
            Rr[4 * q + 0] = v.x; Rr[4 * q + 1] = v.y;
            Rr[4 * q + 2] = v.z; Rr[4 * q + 3] = v.w;
        }
    }
    __syncthreads();

    // scan
    for (int e = tid; e < NEDGE; e += 512) {
        const int* cp; int i, dest;
        if (e < 25600)      { cp = qlc;  i = e;         dest = i / 200; }
        else if (e < 51200) { cp = qrc;  i = e - 25600; dest = 128 + i / 200; }
        else if (e < 52200) { cp = slc;  i = e - 51200; dest = 256 + i / 200; }
        else                { cp = srcn; i = e - 52200; dest = 261 + i / 200; }
        const int2 ce = reinterpret_cast<const int2*>(cp)[i];  // {rel, ent}
        if (ce.x == r) {
            const int slot = atomicAdd(&lcnt, 1);
            if (slot < CAP) lst[slot] = make_int2(ce.y, (e << 9) | dest);
        }
    }
    __syncthreads();

    const int cnt = min(lcnt, CAP);
    float* stage = ws + OFF_STAGE;
    float* msg   = ws + OFF_MSG;

    for (int m = wave; m < cnt; m += 8) {
        const int2 ed  = lst[m];
        const int ent  = __builtin_amdgcn_readfirstlane(ed.x);
        const int meta = __builtin_amdgcn_readfirstlane(ed.y);
        const float4* ep = reinterpret_cast<const float4*>(ent_emb + (size_t)ent * 64);
        float acc = 0.f;
#pragma unroll
        for (int q = 0; q < 16; ++q) {
            const float4 ev = ep[q];
            acc = fmaf(Rr[4 * q + 0], ev.x, acc);
            acc = fmaf(Rr[4 * q + 1], ev.y, acc);
            acc = fmaf(Rr[4 * q + 2], ev.z, acc);
            acc = fmaf(Rr[4 * q + 3], ev.w, acc);
        }
        if (STAGED) {
            const int e = meta >> 9;
            stage[(size_t)e * 64 + lane] = acc;
        } else {
            const int dest = meta & 511;
            atomicAdd(&msg[dest * 64 + lane], acc);
        }
    }
}

// ---------------------------------------------------------------------------
// k_post: 133 blocks x 256 threads. Per block = one feature row (query b or
// support f): reduce stage rows (or read msg) -> project (gcn) -> MLP+LN
// encoder -> QG/SG. Also packs lstm weights to bf16 pairs (independent work).
// ---------------------------------------------------------------------------
template<bool STAGED>
__global__ __launch_bounds__(256) void k_post(
    const float* __restrict__ gcn_w, const float* __restrict__ gcn_wb,
    const float* __restrict__ gcn_b,
    const float* __restrict__ qld, const float* __restrict__ qrd,
    const float* __restrict__ sld, const float* __restrict__ srd,
    const float* __restrict__ w1, const float* __restrict__ b1,
    const float* __restrict__ w2, const float* __restrict__ b2,
    const float* __restrict__ lng, const float* __restrict__ lnb,
    const float* __restrict__ whh, const float* __restrict__ wih,
    float* __restrict__ ws)
{
    const int blk = blockIdx.x, t = threadIdx.x;

    // ---- lstm weight pack (independent; live gate units only) ----
    {
        unsigned* whhp = (unsigned*)(ws + OFF_WHHP);
        unsigned* wihp = (unsigned*)(ws + OFF_WIHP);
        for (int idx = blk * 256 + t; idx < 98304; idx += 133 * 256) {
            if (idx < 65536) {
                const int v = idx & 511, jp = idx >> 9;
                const int u = ((v >> 7) << 8) + (v & 127);
                whhp[jp * 512 + v] = bf16_rne(whh[(2 * jp) * 1024 + u]) |
                                     (bf16_rne(whh[(2 * jp + 1) * 1024 + u]) << 16);
            } else {
                const int g2 = idx - 65536;
                const int v = g2 & 511, jp = g2 >> 9;
                const int u = ((v >> 7) << 8) + (v & 127);
                wihp[jp * 512 + v] = bf16_rne(wih[(2 * jp) * 1024 + u]) |
                                     (bf16_rne(wih[(2 * jp + 1) * 1024 + u]) << 16);
            }
        }
    }

    __shared__ float mm[128];   // summed msg, [L half | R half]
    __shared__ float x[128];    // projected features
    __shared__ float h1[256];
    __shared__ float hh[128];
    __shared__ float red[8];

    float deg = 1.f;
    if (t < 128) {
        const int half = t >> 6, col = t & 63;
        float s = 0.f;
        const float* degp;
        if (STAGED) {
            int e0;
            if (blk < 128) { e0 = half ? 25600 + blk * 200 : blk * 200;
                             degp = half ? qrd + blk : qld + blk; }
            else { const int f = blk - 128;
                   e0 = half ? 52200 + f * 200 : 51200 + f * 200;
                   degp = half ? srd + f : sld + f; }
            const float* sp = ws + OFF_STAGE + (size_t)e0 * 64 + col;
#pragma unroll 8
            for (int n = 0; n < 200; ++n) s += sp[n * 64];
        } else {
            int dest;
            if (blk < 128) { dest = half ? 128 + blk : blk;
                             degp = half ? qrd + blk : qld + blk; }
            else { const int f = blk - 128;
                   dest = half ? 261 + f : 256 + f;
                   degp = half ? srd + f : sld + f; }
            s = ws[OFF_MSG + dest * 64 + col];
        }
        mm[t] = s;
        deg = degp[0];
    }
    __syncthreads();

    // projection: x[t] = tanh((mm_half . gcn_w[:,col] + 200*(wb+b)[col]) / deg)
    if (t < 128) {
        const int col = t & 63, base = t & 64;
        float s = 0.f;
#pragma unroll 8
        for (int j = 0; j < 64; ++j) s = fmaf(mm[base + j], gcn_w[j * 64 + col], s);
        s += 200.f * (gcn_wb[col] + gcn_b[col]);
        x[t] = tanhf(s / deg);
    }
    __syncthreads();

    // encoder: h1 = relu(x@w1+b1)
    {
        float s = b1[t];
#pragma unroll 8
        for (int j = 0; j < 128; ++j) s = fmaf(x[j], w1[j * 256 + t], s);
        h1[t] = fmaxf(s, 0.f);
    }
    __syncthreads();

    if (t < 128) {
        float s = b2[t] + x[t];
#pragma unroll 8
        for (int k = 0; k < 256; ++k) s = fmaf(h1[k], w2[k * 128 + t], s);
        hh[t] = s;
    }
    __syncthreads();

    // LayerNorm ddof=1
    float v = (t < 128) ? hh[t] : 0.f;
#pragma unroll
    for (int m = 32; m >= 1; m >>= 1) v += __shfl_xor(v, m);
    if ((t & 63) == 0) red[t >> 6] = v;
    __syncthreads();
    const float mu = (red[0] + red[1]) * (1.f / 128.f);
    float d = (t < 128) ? (hh[t] - mu) : 0.f;
    float v2 = d * d;
#pragma unroll
    for (int m = 32; m >= 1; m >>= 1) v2 += __shfl_xor(v2, m);
    if ((t & 63) == 0) red[4 + (t >> 6)] = v2;
    __syncthreads();
    const float var = (red[4] + red[5]) * (1.f / 127.f);
    const float rs = 1.f / (sqrtf(var) + 0.001f);
    if (t < 128) {
        float* xout = (blk < 128) ? ws + OFF_QG + blk * 128 : ws + OFF_SG + (blk - 128) * 128;
        xout[t] = (hh[t] - mu) * rs * lng[t] + lnb[t];
    }
}

// ---------------------------------------------------------------------------
// k_lstm: 64 blocks x 512 threads, 2 batch rows/block; 512 live gate units
// (h_r_[:,128:256] is dead in the reference). bf16-packed weights.
// ---------------------------------------------------------------------------
__global__ __launch_bounds__(512) void k_lstm(
    const float* __restrict__ bih, const float* __restrict__ bhh,
    float* __restrict__ ws, float* __restrict__ outp)
{
    const int t  = threadIdx.x;
    const int b0 = blockIdx.x * 2;
    const unsigned* whhp = (const unsigned*)(ws + OFF_WHHP);
    const unsigned* wihp = (const unsigned*)(ws + OFF_WIHP);
    const float* query_g = ws + OFF_QG;
    const float* sgp     = ws + OFF_SG;

    __shared__ float  sgf[5 * 128];
    __shared__ float2 qg2[2][64];
    __shared__ float2 hr2[2][128];
    __shared__ float  gbuf[2][512];
    __shared__ float  redw[4][5];

    float* qg = (float*)qg2;
    float* hr = (float*)hr2;

    for (int i = t; i < 640; i += 512) sgf[i] = sgp[i];
    if (t < 256) qg[(t >> 7) * 128 + (t & 127)] = query_g[(size_t)(b0 + (t >> 7)) * 128 + (t & 127)];
    hr[t] = 0.f;

    const int v = t;
    const int u = ((v >> 7) << 8) + (v & 127);

    float xp[2];
    xp[0] = bih[u] + bhh[u];
    xp[1] = xp[0];
    __syncthreads();

#pragma unroll 8
    for (int jp = 0; jp < 64; ++jp) {
        const unsigned w = wihp[jp * 512 + v];
        const float f0 = __uint_as_float(w << 16);
        const float f1 = __uint_as_float(w & 0xffff0000u);
        const float2 q0 = qg2[0][jp], q1 = qg2[1][jp];
        xp[0] = fmaf(f0, q0.x, fmaf(f1, q0.y, xp[0]));
        xp[1] = fmaf(f0, q1.x, fmaf(f1, q1.y, xp[1]));
    }

    float c = 0.f;
    const int bp = (t >> 7) & 1, tp = t & 127;

    for (int step = 0; step < 4; ++step) {
        float ga[2];
        ga[0] = xp[0]; ga[1] = xp[1];
#pragma unroll 8
        for (int jp = 0; jp < 128; ++jp) {
            const unsigned w = whhp[jp * 512 + v];
            const float f0 = __uint_as_float(w << 16);
            const float f1 = __uint_as_float(w & 0xffff0000u);
            const float2 h0 = hr2[0][jp], h1 = hr2[1][jp];
            ga[0] = fmaf(f0, h0.x, fmaf(f1, h0.y, ga[0]));
            ga[1] = fmaf(f0, h1.x, fmaf(f1, h1.y, ga[1]));
        }
        gbuf[0][v] = ga[0];
        gbuf[1][v] = ga[1];
        __syncthreads();

        float hv = 0.f;
        if (t < 256) {
            const float iv = sigm(gbuf[bp][tp]);
            const float fv = sigm(gbuf[bp][128 + tp]);
            const float gv = tanhf(gbuf[bp][256 + tp]);
            const float ov = sigm(gbuf[bp][384 + tp]);
            c = fv * c + iv * gv;
            hv = qg[bp * 128 + tp] + ov * tanhf(c);
            hr[bp * 256 + tp] = hv;
        }

        float p0 = 0, p1 = 0, p2 = 0, p3 = 0, p4 = 0;
        if (t < 256) {
            p0 = hv * sgf[0 * 128 + tp];
            p1 = hv * sgf[1 * 128 + tp];
            p2 = hv * sgf[2 * 128 + tp];
            p3 = hv * sgf[3 * 128 + tp];
            p4 = hv * sgf[4 * 128 + tp];
#pragma unroll
            for (int m = 32; m >= 1; m >>= 1) {
                p0 += __shfl_xor(p0, m);
                p1 += __shfl_xor(p1, m);
                p2 += __shfl_xor(p2, m);
                p3 += __shfl_xor(p3, m);
                p4 += __shfl_xor(p4, m);
            }
            if ((t & 63) == 0) {
                const int w = t >> 6;
                redw[w][0] = p0; redw[w][1] = p1; redw[w][2] = p2;
                redw[w][3] = p3; redw[w][4] = p4;
            }
        }
        __syncthreads();

        if (step == 3) {
            if (t < 10) {
                const int bl = t / 5, s = t % 5;
                outp[(size_t)(b0 + bl) * 5 + s] = redw[2 * bl][s] + redw[2 * bl + 1][s];
            }
        }
        if (t < 256) {
            const float d0 = redw[2 * bp][0] + redw[2 * bp + 1][0];
            const float d1 = redw[2 * bp][1] + redw[2 * bp + 1][1];
            const float d2 = redw[2 * bp][2] + redw[2 * bp + 1][2];
            const float d3 = redw[2 * bp][3] + redw[2 * bp + 1][3];
            const float d4 = redw[2 * bp][4] + redw[2 * bp + 1][4];
            const float mx = fmaxf(fmaxf(fmaxf(d0, d1), fmaxf(d2, d3)), d4);
            const float e0 = __expf(d0 - mx), e1 = __expf(d1 - mx), e2 = __expf(d2 - mx),
                        e3 = __expf(d3 - mx), e4 = __expf(d4 - mx);
            const float inv = 1.f / (e0 + e1 + e2 + e3 + e4);
            const float rv = (e0 * sgf[0 * 128 + tp] + e1 * sgf[1 * 128 + tp] +
                              e2 * sgf[2 * 128 + tp] + e3 * sgf[3 * 128 + tp] +
                              e4 * sgf[4 * 128 + tp]) * inv;
            hr[bp * 256 + 128 + tp] = rv;
        }
        __syncthreads();
    }
}

// ---------------------------------------------------------------------------
extern "C" void kernel_launch(void* const* d_in, const int* in_sizes, int n_in,
                              void* d_out, int out_size, void* d_ws, size_t ws_size,
                              hipStream_t stream) {
    const int*   qlc = (const int*)d_in[0];
    const int*   qrc = (const int*)d_in[1];
    const int*   slc = (const int*)d_in[2];
    const int*   srcn= (const int*)d_in[3];
    const float* qld = (const float*)d_in[4];
    const float* qrd = (const float*)d_in[5];
    const float* sld = (const float*)d_in[6];
    const float* srd = (const float*)d_in[7];
    const float* ent = (const float*)d_in[8];
    const float* rel = (const float*)d_in[9];
    const float* gw  = (const float*)d_in[10];
    const float* gwb = (const float*)d_in[11];
    const float* gb  = (const float*)d_in[12];
    const float* w1  = (const float*)d_in[13];
    const float* b1  = (const float*)d_in[14];
    const float* w2  = (const float*)d_in[15];
    const float* b2  = (const float*)d_in[16];
    const float* lng = (const float*)d_in[17];
    const float* lnb = (const float*)d_in[18];
    const float* wih = (const float*)d_in[19];
    const float* whh = (const float*)d_in[20];
    const float* bih = (const float*)d_in[21];
    const float* bhh = (const float*)d_in[22];

    float* ws   = (float*)d_ws;
    float* outp = (float*)d_out;

    const bool staged = ws_size >= (size_t)NEED_FLOATS * sizeof(float);

    if (staged) {
        hipLaunchKernelGGL(k_gather<true>, dim3(NREL), dim3(512), 0, stream,
                           qlc, qrc, slc, srcn, rel, ent, ws);
        hipLaunchKernelGGL(k_post<true>, dim3(133), dim3(256), 0, stream,
                           gw, gwb, gb, qld, qrd, sld, srd,
                           w1, b1, w2, b2, lng, lnb, whh, wih, ws);
    } else {
        hipLaunchKernelGGL(k_zero, dim3(34), dim3(512), 0, stream, ws);
        hipLaunchKernelGGL(k_gather<false>, dim3(NREL), dim3(512), 0, stream,
                           qlc, qrc, slc, srcn, rel, ent, ws);
        hipLaunchKernelGGL(k_post<false>, dim3(133), dim3(256), 0, stream,
                           gw, gwb, gb, qld, qrd, sld, srd,
                           w1, b1, w2, b2, lng, lnb, whh, wih, ws);
    }
    hipLaunchKernelGGL(k_lstm, dim3(64), dim3(512), 0, stream, bih, bhh, ws, outp);
}

// Round 6
// 194.318 us; speedup vs baseline: 1.5972x; 1.1013x over previous
//
#include <hip/hip_runtime.h>
#include <math.h>

#define NREL 500
#define CAP  256
#define NEDGE 53200   // qlc [0,25600) qrc [25600,51200) slc [51200,52200) srcn [52200,53200)

__device__ __forceinline__ float sigm(float x) { return 1.0f / (1.0f + __expf(-x)); }
__device__ __forceinline__ unsigned bf16_rne(float x) {
    unsigned b = __float_as_uint(x);
    return (b + 0x7fffu + ((b >> 16) & 1u)) >> 16;
}

// ws layout (float offsets), total 2,074,240 floats = 8.0 MiB (known-safe: R5 ran 13.5 MiB)
#define OFF_COUNTS 0              // 512 uints (atomic targets; NEVER zeroed — poison-tolerant)
#define OFF_LIST   512            // 500*256 int2 = 256000
#define OFF_WHHP   256512         // 128*512 uint (bf16 pairs, live cols)
#define OFF_WIHP   322048         // 64*512 uint
#define OFF_QG     354816         // 128*128
#define OFF_SG     371200         // 5*128
#define OFF_STAGE  371840         // 53200*32 uint (bf16 pairs per edge row)

// ---------------------------------------------------------------------------
// K1 k_build: (a) scatter 53200 edges into per-rel tagged lists; (b) pack lstm
// weights to bf16 pairs. Counts start at POISON (0xAAAAAAAA) — we never zero:
// slot = raw_atomic_return % CAP is consecutive per rel regardless of base, and
// entries carry tag 0x5 + validated fields, so unwritten (poison) slots are
// rejected by k_gather. 296 blocks x 512.
// ---------------------------------------------------------------------------
__global__ __launch_bounds__(512) void k_build(
    const int* __restrict__ qlc, const int* __restrict__ qrc,
    const int* __restrict__ slc, const int* __restrict__ srcn,
    const float* __restrict__ whh, const float* __restrict__ wih,
    float* __restrict__ ws)
{
    const int idx = blockIdx.x * 512 + threadIdx.x;
    if (idx < NEDGE) {
        unsigned* counts = (unsigned*)(ws + OFF_COUNTS);
        int2* list2 = (int2*)(ws + OFF_LIST);
        const int e = idx;
        const int* cp; int i, dest;
        if (e < 25600)      { cp = qlc;  i = e;         dest = i / 200; }
        else if (e < 51200) { cp = qrc;  i = e - 25600; dest = 128 + i / 200; }
        else if (e < 52200) { cp = slc;  i = e - 51200; dest = 256 + i / 200; }
        else                { cp = srcn; i = e - 52200; dest = 261 + i / 200; }
        const int rel = cp[2 * i];
        const int ent = cp[2 * i + 1];
        const unsigned ret = atomicAdd(&counts[rel], 1u);
        const int slot = (int)(ret & (CAP - 1));
        const int meta = 0x50000000 | (e << 9) | dest;
        list2[rel * CAP + slot] = make_int2(ent, meta);
    } else if (idx < NEDGE + 98304) {
        unsigned* whhp = (unsigned*)(ws + OFF_WHHP);
        unsigned* wihp = (unsigned*)(ws + OFF_WIHP);
        const int p = idx - NEDGE;
        if (p < 65536) {                    // whh: 128 jp x 512 v
            const int v = p & 511, jp = p >> 9;
            const int u = ((v >> 7) << 8) + (v & 127);
            whhp[jp * 512 + v] = bf16_rne(whh[(2 * jp) * 1024 + u]) |
                                 (bf16_rne(whh[(2 * jp + 1) * 1024 + u]) << 16);
        } else {                            // wih: 64 jp x 512 v
            const int g2 = p - 65536;
            const int v = g2 & 511, jp = g2 >> 9;
            const int u = ((v >> 7) << 8) + (v & 127);
            wihp[jp * 512 + v] = bf16_rne(wih[(2 * jp) * 1024 + u]) |
                                 (bf16_rne(wih[(2 * jp + 1) * 1024 + u]) << 16);
        }
    }
}

// ---------------------------------------------------------------------------
// K2 k_gather: 500 blocks x 256 threads (4 waves). Lane i keeps R[r][i][0:64]
// in 64 VGPRs (launch_bounds(256,2) -> VGPR budget 256, no spill). Compact
// valid tagged entries to LDS once, then per edge: wave-uniform e-loads +
// 2 independent 32-deep fma chains. Stage written as bf16 pairs (no atomics,
// no zero-init: every edge row written exactly once).
// ---------------------------------------------------------------------------
__global__ __launch_bounds__(256, 2) void k_gather(
    const float* __restrict__ rel_mat, const float* __restrict__ ent_emb,
    float* __restrict__ ws)
{
    const int r    = blockIdx.x;
    const int tid  = threadIdx.x;
    const int wave = tid >> 6, lane = tid & 63;
    const int2* list2 = (const int2*)(ws + OFF_LIST) + r * CAP;
    unsigned* stage_u = (unsigned*)(ws + OFF_STAGE);

    __shared__ int2 lst[CAP];
    __shared__ int  lcnt;
    if (tid == 0) lcnt = 0;

    // R row for this lane (each of 4 waves holds a full copy; L2-resident)
    float Rr[64];
    {
        const float4* Rp = reinterpret_cast<const float4*>(rel_mat + (size_t)r * 4096 + lane * 64);
#pragma unroll
        for (int q = 0; q < 16; ++q) {
            const float4 v = Rp[q];
            Rr[4 * q + 0] = v.x; Rr[4 * q + 1] = v.y;
            Rr[4 * q + 2] = v.z; Rr[4 * q + 3] = v.w;
        }
    }
    __syncthreads();   // lcnt=0 visible

    // compact valid entries (tag 0x5 + field validation rejects poison)
    {
        const int2 en = list2[tid];
        const int meta = en.y;
        const int e = (meta >> 9) & 0xffff, dest = meta & 511;
        const bool ok = ((meta >> 28) & 0xf) == 0x5 && e < NEDGE && dest < 266 &&
                        en.x >= 0 && en.x <= 50000;
        if (ok) {
            const int s = atomicAdd(&lcnt, 1);
            lst[s] = en;
        }
    }
    __syncthreads();
    const int cnt = lcnt;

    for (int m = wave; m < cnt; m += 4) {
        const int2 ed = lst[m];
        const int ent = __builtin_amdgcn_readfirstlane(ed.x);
        const int e   = __builtin_amdgcn_readfirstlane((ed.y >> 9) & 0xffff);
        const float4* ep = reinterpret_cast<const float4*>(ent_emb + (size_t)ent * 64);
        float a0 = 0.f, a1 = 0.f;   // two independent chains
#pragma unroll
        for (int q = 0; q < 8; ++q) {
            const float4 e0 = ep[2 * q];
            const float4 e1 = ep[2 * q + 1];
            a0 = fmaf(Rr[8 * q + 0], e0.x, a0);
            a0 = fmaf(Rr[8 * q + 1], e0.y, a0);
            a0 = fmaf(Rr[8 * q + 2], e0.z, a0);
            a0 = fmaf(Rr[8 * q + 3], e0.w, a0);
            a1 = fmaf(Rr[8 * q + 4], e1.x, a1);
            a1 = fmaf(Rr[8 * q + 5], e1.y, a1);
            a1 = fmaf(Rr[8 * q + 6], e1.z, a1);
            a1 = fmaf(Rr[8 * q + 7], e1.w, a1);
        }
        const float acc = a0 + a1;
        const float par = __shfl_xor(acc, 1);
        if (!(lane & 1)) {   // even lane packs cols (lane, lane+1)
            const unsigned u = bf16_rne(acc) | (bf16_rne(par) << 16);
            stage_u[(size_t)e * 32 + (lane >> 1)] = u;
        }
    }
}

// ---------------------------------------------------------------------------
// K3 k_post: 133 blocks x 256. Reduce bf16 stage rows (4-way split over n) ->
// gcn projection -> MLP + residual + LayerNorm(ddof=1) -> QG/SG.
// ---------------------------------------------------------------------------
__global__ __launch_bounds__(256) void k_post(
    const float* __restrict__ gcn_w, const float* __restrict__ gcn_wb,
    const float* __restrict__ gcn_b,
    const float* __restrict__ qld, const float* __restrict__ qrd,
    const float* __restrict__ sld, const float* __restrict__ srd,
    const float* __restrict__ w1, const float* __restrict__ b1,
    const float* __restrict__ w2, const float* __restrict__ b2,
    const float* __restrict__ lng, const float* __restrict__ lnb,
    float* __restrict__ ws)
{
    const int blk = blockIdx.x, t = threadIdx.x;
    const unsigned* stage_u = (const unsigned*)(ws + OFF_STAGE);

    __shared__ float mm[128];    // summed msg [L 64 | R 64]
    __shared__ float degs[2];
    __shared__ float x[128];
    __shared__ float h1[256];
    __shared__ float hh[128];
    __shared__ float red[8];

    if (t < 128) mm[t] = 0.f;
    if (t < 2) {
        const float* dp;
        if (blk < 128) dp = t ? qrd + blk : qld + blk;
        else           dp = t ? srd + (blk - 128) : sld + (blk - 128);
        degs[t] = dp[0];
    }
    __syncthreads();

    {   // stage reduce: (half, cp in [0,32), quarter q in [0,4))
        const int half = t >> 7, rr = t & 127, cp = rr >> 2, q = rr & 3;
        int e0;
        if (blk < 128) e0 = half ? 25600 + blk * 200 : blk * 200;
        else { const int f = blk - 128; e0 = half ? 52200 + f * 200 : 51200 + f * 200; }
        const unsigned* sp = stage_u + (size_t)(e0 + q * 50) * 32 + cp;
        float slo = 0.f, shi = 0.f;
#pragma unroll 10
        for (int n = 0; n < 50; ++n) {
            const unsigned u = sp[n * 32];
            slo += __uint_as_float(u << 16);
            shi += __uint_as_float(u & 0xffff0000u);
        }
        atomicAdd(&mm[half * 64 + 2 * cp], slo);
        atomicAdd(&mm[half * 64 + 2 * cp + 1], shi);
    }
    __syncthreads();

    // projection
    if (t < 128) {
        const int col = t & 63, base = t & 64;
        float s = 0.f;
#pragma unroll 8
        for (int j = 0; j < 64; ++j) s = fmaf(mm[base + j], gcn_w[j * 64 + col], s);
        s += 200.f * (gcn_wb[col] + gcn_b[col]);
        x[t] = tanhf(s / degs[t >> 6]);
    }
    __syncthreads();

    // encoder
    {
        float s = b1[t];
#pragma unroll 8
        for (int j = 0; j < 128; ++j) s = fmaf(x[j], w1[j * 256 + t], s);
        h1[t] = fmaxf(s, 0.f);
    }
    __syncthreads();
    if (t < 128) {
        float s = b2[t] + x[t];
#pragma unroll 8
        for (int k = 0; k < 256; ++k) s = fmaf(h1[k], w2[k * 128 + t], s);
        hh[t] = s;
    }
    __syncthreads();

    // LayerNorm ddof=1
    float v = (t < 128) ? hh[t] : 0.f;
#pragma unroll
    for (int m = 32; m >= 1; m >>= 1) v += __shfl_xor(v, m);
    if ((t & 63) == 0) red[t >> 6] = v;
    __syncthreads();
    const float mu = (red[0] + red[1]) * (1.f / 128.f);
    float d = (t < 128) ? (hh[t] - mu) : 0.f;
    float v2 = d * d;
#pragma unroll
    for (int m = 32; m >= 1; m >>= 1) v2 += __shfl_xor(v2, m);
    if ((t & 63) == 0) red[4 + (t >> 6)] = v2;
    __syncthreads();
    const float var = (red[4] + red[5]) * (1.f / 127.f);
    const float rs = 1.f / (sqrtf(var) + 0.001f);
    if (t < 128) {
        float* xout = (blk < 128) ? ws + OFF_QG + blk * 128 : ws + OFF_SG + (blk - 128) * 128;
        xout[t] = (hh[t] - mu) * rs * lng[t] + lnb[t];
    }
}

// ---------------------------------------------------------------------------
// K4 k_lstm: 128 blocks x 512 (one batch row per block). Thread t owns live
// gate unit t (cells 0..127 x {i,f,g,o}); dead cells 128..255 skipped. Four
// independent fma chains; unroll-4 pipelined bf16-pair loads.
// ---------------------------------------------------------------------------
__global__ __launch_bounds__(512) void k_lstm(
    const float* __restrict__ bih, const float* __restrict__ bhh,
    float* __restrict__ ws, float* __restrict__ outp)
{
    const int t = threadIdx.x;
    const int b = blockIdx.x;
    const unsigned* whhp = (const unsigned*)(ws + OFF_WHHP);
    const unsigned* wihp = (const unsigned*)(ws + OFF_WIHP);

    __shared__ float sgf[5 * 128];
    __shared__ float qg[128];
    __shared__ float hr[256];     // h | r
    __shared__ float gbuf[512];
    __shared__ float redw[2][5];

    for (int i = t; i < 640; i += 512) sgf[i] = (ws + OFF_SG)[i];
    if (t < 128) qg[t] = (ws + OFF_QG)[(size_t)b * 128 + t];
    if (t < 256) hr[t] = 0.f;

    const int u = ((t >> 7) << 8) + (t & 127);
    float xp = bih[u] + bhh[u];
    __syncthreads();

    const float2* qg2 = (const float2*)qg;
    const float2* hr2 = (const float2*)hr;

#pragma unroll 8
    for (int jp = 0; jp < 64; ++jp) {
        const unsigned w = wihp[jp * 512 + t];
        const float2 q = qg2[jp];
        xp = fmaf(__uint_as_float(w << 16), q.x,
             fmaf(__uint_as_float(w & 0xffff0000u), q.y, xp));
    }

    float c = 0.f;
    const int tp = t & 127;

    for (int step = 0; step < 4; ++step) {
        float g0 = xp, g1 = 0.f, g2 = 0.f, g3 = 0.f;
#pragma unroll 4
        for (int jp = 0; jp < 128; jp += 4) {
            const unsigned w0 = whhp[(jp + 0) * 512 + t];
            const unsigned w1 = whhp[(jp + 1) * 512 + t];
            const unsigned w2 = whhp[(jp + 2) * 512 + t];
            const unsigned w3 = whhp[(jp + 3) * 512 + t];
            const float2 h0 = hr2[jp + 0], h1 = hr2[jp + 1];
            const float2 h2 = hr2[jp + 2], h3 = hr2[jp + 3];
            g0 = fmaf(__uint_as_float(w0 << 16), h0.x, fmaf(__uint_as_float(w0 & 0xffff0000u), h0.y, g0));
            g1 = fmaf(__uint_as_float(w1 << 16), h1.x, fmaf(__uint_as_float(w1 & 0xffff0000u), h1.y, g1));
            g2 = fmaf(__uint_as_float(w2 << 16), h2.x, fmaf(__uint_as_float(w2 & 0xffff0000u), h2.y, g2));
            g3 = fmaf(__uint_as_float(w3 << 16), h3.x, fmaf(__uint_as_float(w3 & 0xffff0000u), h3.y, g3));
        }
        gbuf[t] = (g0 + g1) + (g2 + g3);
        __syncthreads();   // gates ready; hr reads done

        float hv = 0.f;
        if (t < 128) {
            const float iv = sigm(gbuf[tp]);
            const float fv = sigm(gbuf[128 + tp]);
            const float gv = tanhf(gbuf[256 + tp]);
            const float ov = sigm(gbuf[384 + tp]);
            c = fv * c + iv * gv;
            hv = qg[tp] + ov * tanhf(c);
            hr[tp] = hv;
        }

        // dots h . support_s over 128 cols (2 waves)
        float p0 = 0, p1 = 0, p2 = 0, p3 = 0, p4 = 0;
        if (t < 128) {
            p0 = hv * sgf[0 * 128 + tp];
            p1 = hv * sgf[1 * 128 + tp];
            p2 = hv * sgf[2 * 128 + tp];
            p3 = hv * sgf[3 * 128 + tp];
            p4 = hv * sgf[4 * 128 + tp];
#pragma unroll
            for (int m = 32; m >= 1; m >>= 1) {
                p0 += __shfl_xor(p0, m);
                p1 += __shfl_xor(p1, m);
                p2 += __shfl_xor(p2, m);
                p3 += __shfl_xor(p3, m);
                p4 += __shfl_xor(p4, m);
            }
            if ((t & 63) == 0) {
                const int w = t >> 6;
                redw[w][0] = p0; redw[w][1] = p1; redw[w][2] = p2;
                redw[w][3] = p3; redw[w][4] = p4;
            }
        }
        __syncthreads();

        const float d0 = redw[0][0] + redw[1][0];
        const float d1 = redw[0][1] + redw[1][1];
        const float d2 = redw[0][2] + redw[1][2];
        const float d3 = redw[0][3] + redw[1][3];
        const float d4 = redw[0][4] + redw[1][4];

        if (step == 3) {
            if (t == 0) {
                float* o = outp + (size_t)b * 5;
                o[0] = d0; o[1] = d1; o[2] = d2; o[3] = d3; o[4] = d4;
            }
        }
        if (t < 128) {
            const float mx = fmaxf(fmaxf(fmaxf(d0, d1), fmaxf(d2, d3)), d4);
            const float e0 = __expf(d0 - mx), e1 = __expf(d1 - mx), e2 = __expf(d2 - mx),
                        e3 = __expf(d3 - mx), e4 = __expf(d4 - mx);
            const float inv = 1.f / (e0 + e1 + e2 + e3 + e4);
            hr[128 + tp] = (e0 * sgf[0 * 128 + tp] + e1 * sgf[1 * 128 + tp] +
                            e2 * sgf[2 * 128 + tp] + e3 * sgf[3 * 128 + tp] +
                            e4 * sgf[4 * 128 + tp]) * inv;
        }
        __syncthreads();
    }
}

// ---------------------------------------------------------------------------
extern "C" void kernel_launch(void* const* d_in, const int* in_sizes, int n_in,
                              void* d_out, int out_size, void* d_ws, size_t ws_size,
                              hipStream_t stream) {
    const int*   qlc = (const int*)d_in[0];
    const int*   qrc = (const int*)d_in[1];
    const int*   slc = (const int*)d_in[2];
    const int*   srcn= (const int*)d_in[3];
    const float* qld = (const float*)d_in[4];
    const float* qrd = (const float*)d_in[5];
    const float* sld = (const float*)d_in[6];
    const float* srd = (const float*)d_in[7];
    const float* ent = (const float*)d_in[8];
    const float* rel = (const float*)d_in[9];
    const float* gw  = (const float*)d_in[10];
    const float* gwb = (const float*)d_in[11];
    const float* gb  = (const float*)d_in[12];
    const float* w1  = (const float*)d_in[13];
    const float* b1  = (const float*)d_in[14];
    const float* w2  = (const float*)d_in[15];
    const float* b2  = (const float*)d_in[16];
    const float* lng = (const float*)d_in[17];
    const float* lnb = (const float*)d_in[18];
    const float* wih = (const float*)d_in[19];
    const float* whh = (const float*)d_in[20];
    const float* bih = (const float*)d_in[21];
    const float* bhh = (const float*)d_in[22];

    float* ws   = (float*)d_ws;
    float* outp = (float*)d_out;

    hipLaunchKernelGGL(k_build,  dim3(296), dim3(512), 0, stream,
                       qlc, qrc, slc, srcn, whh, wih, ws);
    hipLaunchKernelGGL(k_gather, dim3(NREL), dim3(256), 0, stream, rel, ent, ws);
    hipLaunchKernelGGL(k_post,   dim3(133), dim3(256), 0, stream,
                       gw, gwb, gb, qld, qrd, sld, srd,
                       w1, b1, w2, b2, lng, lnb, ws);
    hipLaunchKernelGGL(k_lstm,   dim3(128), dim3(512), 0, stream, bih, bhh, ws, outp);
}